// Round 1
// baseline (143.034 us; speedup 1.0000x reference)
//
#include <hip/hip_runtime.h>
#include <math.h>

static constexpr int BB  = 64;
static constexpr int DIN = 5000;
static constexpr int NHID = 1000;
static constexpr int NG  = 512;
static constexpr int NK  = 8;
static constexpr int NM  = 32;
static constexpr int GS  = 512;
static constexpr int NC  = NK * GS;  // 4096

// split-K GEMM configs
static constexpr int S1 = 16, CHD1 = 320, IT1 = 16, IP1 = 1024;
static constexpr int S2 = 16, CHD2 = 64,  IT2 = 8,  IP2 = 512;

// part[s][b][i] = sum_{d in chunk s} A[b,d] * Bm[i,d]
__global__ __launch_bounds__(256) void gemm64(
    const float* __restrict__ A, int lda,
    const float* __restrict__ Bm, int ldb, int Ireal,
    float* __restrict__ part, int Ipad, int Itiles, int D, int CHD)
{
  __shared__ __align__(16) float xT[32][64];
  __shared__ __align__(16) float wT[32][64];
  const int tid = threadIdx.x;
  const int itile = blockIdx.x % Itiles;
  const int s = blockIdx.x / Itiles;
  const int d_beg = s * CHD;
  const int d_end = min(D, d_beg + CHD);
  const int tx = tid & 15;   // b dimension (b0 = 4*tx)
  const int ty = tid >> 4;   // i dimension (i0 = 4*ty)
  float acc[4][4] = {};

  for (int d0 = d_beg; d0 < d_end; d0 += 32) {
    // stage A chunk transposed: xT[dd][b]
#pragma unroll
    for (int q = 0; q < 2; q++) {
      int lin = q * 256 + tid;
      int r = lin >> 3;
      int c4 = (lin & 7) << 2;
      int d = d0 + c4;
      const float* pr = A + (size_t)r * lda;
      float4 v = make_float4(0.f, 0.f, 0.f, 0.f);
      if (d + 4 <= d_end) v = *(const float4*)(pr + d);
      else {
        if (d + 0 < d_end) v.x = pr[d + 0];
        if (d + 1 < d_end) v.y = pr[d + 1];
        if (d + 2 < d_end) v.z = pr[d + 2];
        if (d + 3 < d_end) v.w = pr[d + 3];
      }
      xT[c4 + 0][r] = v.x; xT[c4 + 1][r] = v.y;
      xT[c4 + 2][r] = v.z; xT[c4 + 3][r] = v.w;
    }
    // stage B chunk transposed: wT[dd][i_local]
#pragma unroll
    for (int q = 0; q < 2; q++) {
      int lin = q * 256 + tid;
      int r = lin >> 3;
      int c4 = (lin & 7) << 2;
      int ib = itile * 64 + r;
      int d = d0 + c4;
      float4 v = make_float4(0.f, 0.f, 0.f, 0.f);
      if (ib < Ireal) {
        const float* pr = Bm + (size_t)ib * ldb;
        if (d + 4 <= d_end) v = *(const float4*)(pr + d);
        else {
          if (d + 0 < d_end) v.x = pr[d + 0];
          if (d + 1 < d_end) v.y = pr[d + 1];
          if (d + 2 < d_end) v.z = pr[d + 2];
          if (d + 3 < d_end) v.w = pr[d + 3];
        }
      }
      wT[c4 + 0][r] = v.x; wT[c4 + 1][r] = v.y;
      wT[c4 + 2][r] = v.z; wT[c4 + 3][r] = v.w;
    }
    __syncthreads();
    const int nn = min(32, d_end - d0);
    if (nn == 32) {
#pragma unroll
      for (int dd = 0; dd < 32; dd++) {
        float4 xv = *(const float4*)&xT[dd][tx << 2];
        float4 wv = *(const float4*)&wT[dd][ty << 2];
        float xr[4] = {xv.x, xv.y, xv.z, xv.w};
        float wr[4] = {wv.x, wv.y, wv.z, wv.w};
#pragma unroll
        for (int a = 0; a < 4; a++)
#pragma unroll
          for (int c = 0; c < 4; c++)
            acc[a][c] = fmaf(xr[a], wr[c], acc[a][c]);
      }
    } else {
      for (int dd = 0; dd < nn; dd++) {
        float4 xv = *(const float4*)&xT[dd][tx << 2];
        float4 wv = *(const float4*)&wT[dd][ty << 2];
        float xr[4] = {xv.x, xv.y, xv.z, xv.w};
        float wr[4] = {wv.x, wv.y, wv.z, wv.w};
#pragma unroll
        for (int a = 0; a < 4; a++)
#pragma unroll
          for (int c = 0; c < 4; c++)
            acc[a][c] = fmaf(xr[a], wr[c], acc[a][c]);
      }
    }
    __syncthreads();
  }

  const int b0 = tx << 2;
  const int i0 = itile * 64 + (ty << 2);
#pragma unroll
  for (int a = 0; a < 4; a++) {
    float4 vv = make_float4(acc[a][0], acc[a][1], acc[a][2], acc[a][3]);
    *(float4*)&part[((size_t)s * BB + (b0 + a)) * Ipad + i0] = vv;
  }
}

// deterministic split-K reduction + bias + activation
// mode 0: relu, mode 1: sigmoid
__global__ void reduce_act(const float* __restrict__ part, int S, int Ipad, int Ireal,
                           const float* __restrict__ bias, float* __restrict__ out,
                           int ostride, int mode)
{
  int lin = blockIdx.x * blockDim.x + threadIdx.x;
  int n = BB * Ireal;
  if (lin >= n) return;
  int b = lin / Ireal;
  int i = lin - b * Ireal;
  float sum = bias[i];
  for (int s = 0; s < S; s++) sum += part[((size_t)s * BB + b) * Ipad + i];
  if (mode == 0) sum = fmaxf(sum, 0.f);
  else           sum = 1.f / (1.f + expf(-sum));
  out[(size_t)b * ostride + i] = sum;
}

// per-sample top-8 (descending, tie -> lower index, matching jax.lax.top_k)
// + fused BCE term2: sum softplus(y) - y*group_labels
__global__ __launch_bounds__(64) void topk_loss2(
    const float* __restrict__ y, const float* __restrict__ gl,
    int* __restrict__ idxo, float* __restrict__ acc)
{
  const int b = blockIdx.x;
  const int lane = threadIdx.x;
  float v[8];
  float l2 = 0.f;
#pragma unroll
  for (int j = 0; j < 8; j++) {
    int pos = j * 64 + lane;
    float z = y[b * NG + pos];
    v[j] = z;
    float t = gl[b * NG + pos];
    l2 += fmaxf(z, 0.f) + log1pf(expf(-fabsf(z))) - z * t;
  }
  for (int k = 0; k < 8; k++) {
    float bv = -INFINITY;
    int bi = 0x7fffffff;
#pragma unroll
    for (int j = 0; j < 8; j++) {
      int pos = j * 64 + lane;
      if (v[j] > bv) { bv = v[j]; bi = pos; }  // ascending pos: first max kept
    }
#pragma unroll
    for (int off = 32; off >= 1; off >>= 1) {
      float ov = __shfl_xor(bv, off, 64);
      int   oi = __shfl_xor(bi, off, 64);
      if (ov > bv || (ov == bv && oi < bi)) { bv = ov; bi = oi; }
    }
    if (lane == 0) idxo[b * NK + k] = bi;
    if (lane == (bi & 63)) {
      int jj = bi >> 6;
#pragma unroll
      for (int j = 0; j < 8; j++) if (j == jj) v[j] = -INFINITY;  // static idx
    }
  }
#pragma unroll
  for (int off = 32; off >= 1; off >>= 1) l2 += __shfl_xor(l2, off, 64);
  if (lane == 0) atomicAdd(acc + 1, l2);
}

// per (b,k): logits[b, k*512+j] = dot(emb[group_y[g*512+j]], y[b]);
// fused new_labels + BCE term1 partial
__global__ __launch_bounds__(512) void score_kernel(
    const float* __restrict__ emb, const float* __restrict__ y,
    const int* __restrict__ idxb, const int* __restrict__ cands,
    const float* __restrict__ labels, const int* __restrict__ group_y,
    float* __restrict__ out, float* __restrict__ acc)
{
  const int bx = blockIdx.x;
  const int b = bx >> 3;
  const int k = bx & 7;
  __shared__ __align__(16) float yl[NG];
  __shared__ int cid[GS];
  __shared__ int tgt[NM];
  __shared__ float red[8];
  const int tid = threadIdx.x;
  const int g = idxb[b * NK + k];
  yl[tid] = y[b * NG + tid];
  cid[tid] = group_y[g * GS + tid];
  if (tid < NM) tgt[tid] = labels[b * NM + tid] > 0.5f ? cands[b * NM + tid] : -1;
  __syncthreads();

  const int l = tid & 15;
  const int grp = tid >> 4;  // 0..31
  const float4* yl4 = (const float4*)yl;
  float lossp = 0.f;

  for (int it = 0; it < 16; it++) {
    int row = it * 32 + grp;
    int r = cid[row];
    const float4* ep = (const float4*)(emb + (size_t)r * NG);
    float sum = 0.f;
#pragma unroll
    for (int seg = 0; seg < 8; seg++) {
      float4 e  = ep[seg * 16 + l];
      float4 yv = yl4[seg * 16 + l];
      sum = fmaf(e.x, yv.x, sum);
      sum = fmaf(e.y, yv.y, sum);
      sum = fmaf(e.z, yv.z, sum);
      sum = fmaf(e.w, yv.w, sum);
    }
    sum += __shfl_xor(sum, 1, 64);
    sum += __shfl_xor(sum, 2, 64);
    sum += __shfl_xor(sum, 4, 64);
    sum += __shfl_xor(sum, 8, 64);
    if (l == 0) {
      out[((size_t)b * NK + k) * GS + row] = sum;
      float nl = 0.f;
#pragma unroll
      for (int m = 0; m < NM; m++) if (r == tgt[m]) nl = 1.f;
      lossp += fmaxf(sum, 0.f) + log1pf(expf(-fabsf(sum))) - sum * nl;
    }
  }
#pragma unroll
  for (int off = 32; off >= 1; off >>= 1) lossp += __shfl_xor(lossp, off, 64);
  const int wid = tid >> 6;
  if ((tid & 63) == 0) red[wid] = lossp;
  __syncthreads();
  if (tid == 0) {
    float t = 0.f;
#pragma unroll
    for (int w = 0; w < 8; w++) t += red[w];
    atomicAdd(acc, t);
  }
}

__global__ void finalize_loss(const float* __restrict__ acc, float* __restrict__ out)
{
  out[(size_t)BB * NC] = acc[0] * (1.f / (float)(BB * NC)) +
                         acc[1] * (1.f / (float)(BB * NG));
}

extern "C" void kernel_launch(void* const* d_in, const int* in_sizes, int n_in,
                              void* d_out, int out_size, void* d_ws, size_t ws_size,
                              hipStream_t stream)
{
  const float* x      = (const float*)d_in[0];
  const int*   cands  = (const int*)  d_in[1];
  const float* labels = (const float*)d_in[2];
  const float* glab   = (const float*)d_in[3];
  const float* W1     = (const float*)d_in[4];
  const float* b1     = (const float*)d_in[5];
  const float* W2     = (const float*)d_in[6];
  const float* b2     = (const float*)d_in[7];
  const float* emb    = (const float*)d_in[8];
  const int*   gy     = (const int*)  d_in[9];
  float* out = (float*)d_out;

  // workspace layout (floats): acc[16] | y[64*512] | idx[512 ints] |
  // h[64*1024] | p1[16*64*1024] | p2[16*64*512]   (~6.7 MB)
  float* ws   = (float*)d_ws;
  float* acc  = ws;
  float* y    = ws + 16;
  int*   idxb = (int*)(y + BB * NG);
  float* h    = (float*)(idxb + 512);
  float* p1   = h + (size_t)BB * IP1;
  float* p2   = p1 + (size_t)S1 * BB * IP1;

  hipMemsetAsync(acc, 0, 2 * sizeof(float), stream);

  // MLP layer 1 (split-K partials, then deterministic reduce + relu)
  gemm64<<<IT1 * S1, 256, 0, stream>>>(x, DIN, W1, DIN, NHID, p1, IP1, IT1, DIN, CHD1);
  reduce_act<<<(BB * NHID + 255) / 256, 256, 0, stream>>>(p1, S1, IP1, NHID, b1, h, IP1, 0);

  // MLP layer 2 + sigmoid
  gemm64<<<IT2 * S2, 256, 0, stream>>>(h, IP1, W2, NHID, NG, p2, IP2, IT2, NHID, CHD2);
  reduce_act<<<(BB * NG + 255) / 256, 256, 0, stream>>>(p2, S2, IP2, NG, b2, y, NG, 1);

  // top-8 groups per sample + BCE term2
  topk_loss2<<<BB, 64, 0, stream>>>(y, glab, idxb, acc);

  // gathered embedding GEMV + new_labels + BCE term1
  score_kernel<<<BB * NK, 512, 0, stream>>>(emb, y, idxb, cands, labels, gy, out, acc);

  finalize_loss<<<1, 1, 0, stream>>>(acc, out);
}